// Round 5
// baseline (185.772 us; speedup 1.0000x reference)
//
#include <hip/hip_runtime.h>

#define NNODES 40000
#define NEDGES 640000
#define PAD 64
#define NBK 800           // dst-range buckets
#define BNODES 50         // nodes per bucket (800*50 = 40000)
#define BCAP 1280         // bucket stream capacity (mean 800, Poisson)
#define AWGS 160
#define ACHUNK 4000       // edges per buildA WG (160*4000 = 640000)
#define GSTR 16           // gcur line-padded stride
// IN_F = 128, HID = 128, OUT_F = 64

typedef unsigned int uint32;
typedef unsigned short ushort16;
typedef short bf16x8 __attribute__((ext_vector_type(8)));
typedef float f32x4 __attribute__((ext_vector_type(4)));

// ---------------- bf16 helpers ----------------
static __device__ __forceinline__ ushort16 f2bf(float f) {
    uint32 u = __builtin_bit_cast(uint32, f);
    uint32 r = u + 0x7fffu + ((u >> 16) & 1u);  // RNE
    return (ushort16)(r >> 16);
}
static __device__ __forceinline__ float bf_lo(uint32 u) {
    uint32 t = u << 16;
    return __builtin_bit_cast(float, t);
}
static __device__ __forceinline__ float bf_hi(uint32 u) {
    uint32 t = u & 0xffff0000u;
    return __builtin_bit_cast(float, t);
}

static __device__ __forceinline__ void acc8(float* s, uint4 u) {
    s[0] += bf_lo(u.x); s[1] += bf_hi(u.x);
    s[2] += bf_lo(u.y); s[3] += bf_hi(u.y);
    s[4] += bf_lo(u.z); s[5] += bf_hi(u.z);
    s[6] += bf_lo(u.w); s[7] += bf_hi(u.w);
}

static __device__ __forceinline__ int edge_val(const void* ep, long long idx, int is64) {
    if (is64) return (int)((const long long*)ep)[idx];
    return ((const int*)ep)[idx];
}

static __device__ __forceinline__ int imin(int a, int b) { return a < b ? a : b; }

// ---------------- fused prep: x -> bf16 AND weight packing + dtype flag + gcur zero ----
// blocks [0, 5000): conv part (n4 = 1,280,000 float4 = exactly 5000*256)
// blocks [5000, 5192): pack part (49152 threads)
__global__ void prep_kernel(const float* __restrict__ x, uint32* __restrict__ xbf2,
                            int* __restrict__ gcur,
                            const float* __restrict__ W1l, const float* __restrict__ W1r,
                            const float* __restrict__ W2l, const float* __restrict__ W2r,
                            ushort16* __restrict__ Wfrag1, ushort16* __restrict__ Wfrag2,
                            const int* __restrict__ e32, int* __restrict__ flag) {
    int b = blockIdx.x;
    if (b < 5000) {
        int i = b * 256 + threadIdx.x;
        float4 v = ((const float4*)x)[i];
        uint2 o;
        o.x = (uint32)f2bf(v.x) | ((uint32)f2bf(v.y) << 16);
        o.y = (uint32)f2bf(v.z) | ((uint32)f2bf(v.w) << 16);
        ((uint2*)xbf2)[i] = o;
        return;
    }
    int i = (b - 5000) * 256 + threadIdx.x;  // 49152 total
    if (i < NBK * GSTR) gcur[i] = 0;
    if (i == 0) {
        int any = 0;
        for (int t = 0; t < 64; ++t) any |= e32[2 * t + 1];
        *flag = (any == 0) ? 1 : 0;
    }
    if (i < 32768) {
        int j = i & 7, lane = (i >> 3) & 63, nt = (i >> 9) & 7, s = (i >> 12) & 3, by = i >> 14;
        int k = s * 32 + (lane >> 4) * 8 + j;
        int col = nt * 16 + (lane & 15);
        float v = (by == 0) ? W1l[k * 128 + col] : W1r[k * 128 + col];
        Wfrag1[i] = f2bf(v);
    } else {
        int q = i - 32768;  // 16384
        int j = q & 7, lane = (q >> 3) & 63, nt = (q >> 9) & 7, s = (q >> 12) & 3;
        int k = s * 32 + (lane >> 4) * 8 + j;
        int col = nt * 16 + (lane & 15);
        float v = (col < 64) ? W2l[k * 64 + col] : W2r[k * 64 + (col - 64)];
        Wfrag2[q] = f2bf(v);
    }
}

// ---------------- buildA: radix partition edges into 800 dst-range bucket streams ----
// Entry packs (src<<8)|dloc, dloc = d - bucket*50 < 50. Per-WG reserved ranges give
// temporal write locality (runs written once by one WG). gcur is line-padded.
__global__ __launch_bounds__(256) void buildA_kernel(const void* __restrict__ edges,
                                                     const int* __restrict__ flag,
                                                     int* __restrict__ gcur,
                                                     int* __restrict__ bstream) {
    __shared__ int hist[NBK];
    __shared__ int cur[NBK];
    int tid = threadIdx.x;
    int base = blockIdx.x * ACHUNK;
    for (int i = tid; i < NBK; i += 256) hist[i] = 0;
    __syncthreads();
    int is64 = *flag;
    // pass 1: count buckets in this chunk
#pragma unroll
    for (int k = 0; k < (ACHUNK + 255) / 256; ++k) {
        int off = k * 256 + tid;
        if (off < ACHUNK) {
            int d = edge_val(edges, (long long)NEDGES + base + off, is64);
            atomicAdd(&hist[d / BNODES], 1);
        }
    }
    __syncthreads();
    for (int i = tid; i < NBK; i += 256) cur[i] = atomicAdd(&gcur[i * GSTR], hist[i]);
    __syncthreads();
    // pass 2: re-read (L2-hot) and append
#pragma unroll
    for (int k = 0; k < (ACHUNK + 255) / 256; ++k) {
        int off = k * 256 + tid;
        if (off < ACHUNK) {
            int e = base + off;
            int d = edge_val(edges, (long long)NEDGES + e, is64);
            int s = edge_val(edges, e, is64);
            int bk = d / BNODES;
            int dloc = d - bk * BNODES;
            int r = atomicAdd(&cur[bk], 1);
            if (r < BCAP) bstream[bk * BCAP + r] = (s << 8) | dloc;
        }
    }
}

// ---------------- MFMA GEMM: C[40000][CO] = Abf[40000][128] @ W ----------------
// block = 256 threads = 4 waves; tile = 64 rows x 128 cols.
// Left cols (< Lw) -> bf16 bfL; right cols -> bf16 bfR (if non-null) else fp32 fR.
__global__ __launch_bounds__(256) void gemm_mfma_kernel(const ushort16* __restrict__ Abf,
                                                        const uint4* __restrict__ WfragG,
                                                        int Lw, int Rw,
                                                        ushort16* __restrict__ bfL,
                                                        ushort16* __restrict__ bfR,
                                                        float* __restrict__ fR) {
    __shared__ uint4 Bs[2048];  // 32 KB
    int tid = threadIdx.x;
#pragma unroll
    for (int it = 0; it < 8; ++it) {
        int idx = tid + it * 256;
        Bs[idx] = WfragG[(size_t)blockIdx.y * 2048 + idx];
    }

    int wv = tid >> 6, lane = tid & 63;
    int quad = lane >> 4, c = lane & 15;
    int row0 = blockIdx.x * 64 + wv * 16;

    const uint4* arow = (const uint4*)(Abf + (size_t)(row0 + c) * 128);
    bf16x8 af[4];
#pragma unroll
    for (int s = 0; s < 4; ++s) af[s] = __builtin_bit_cast(bf16x8, arow[s * 4 + quad]);

    __syncthreads();

    f32x4 acc[8];
#pragma unroll
    for (int nt = 0; nt < 8; ++nt) acc[nt] = (f32x4){0.f, 0.f, 0.f, 0.f};

#pragma unroll
    for (int s = 0; s < 4; ++s) {
#pragma unroll
        for (int nt = 0; nt < 8; ++nt) {
            bf16x8 bf = __builtin_bit_cast(bf16x8, Bs[(s * 8 + nt) * 64 + lane]);
            acc[nt] = __builtin_amdgcn_mfma_f32_16x16x32_bf16(af[s], bf, acc[nt], 0, 0, 0);
        }
    }

    int colbase = blockIdx.y * 128;
#pragma unroll
    for (int nt = 0; nt < 8; ++nt) {
        int gcol = colbase + nt * 16 + c;
#pragma unroll
        for (int r = 0; r < 4; ++r) {
            int row = row0 + quad * 4 + r;
            if (gcol < Lw) {
                bfL[(size_t)row * Lw + gcol] = f2bf(acc[nt][r]);
            } else if (bfR) {
                bfR[(size_t)row * Rw + (gcol - Lw)] = f2bf(acc[nt][r]);
            } else {
                fR[(size_t)row * Rw + (gcol - Lw)] = acc[nt][r];
            }
        }
    }
}

// ---------------- layer-1 aggregation: bucket-WG, LDS CSR regroup + 4-deep gathers ----
// One WG per 50-node bucket: regroup bstream entries into a 12.8 KB LDS CSR image,
// then each wave aggregates nodes nl = wave, wave+4, ... Edge indices come from LDS
// (broadcast) and 4 gathers issue back-to-back (MLP=4).
__global__ __launch_bounds__(256) void agg1_kernel(const uint4* __restrict__ P4,
                                                   const uint4* __restrict__ S4,
                                                   const int* __restrict__ bstream,
                                                   const int* __restrict__ gcur,
                                                   const float* __restrict__ b1,
                                                   uint4* __restrict__ hbf4) {
    __shared__ int img[BNODES * PAD];  // 12.8 KB
    __shared__ int hist[BNODES];
    int tid = threadIdx.x, bk = blockIdx.x;
    for (int i = tid; i < BNODES; i += 256) hist[i] = 0;
    __syncthreads();
    int n = gcur[bk * GSTR];
    if (n > BCAP) n = BCAP;
    for (int i = tid; i < n; i += 256) {
        int u = bstream[bk * BCAP + i];
        int dl = u & 255;
        int r = atomicAdd(&hist[dl], 1);
        if (r < PAD) img[dl * PAD + r] = u >> 8;
    }
    __syncthreads();

    int wave = tid >> 6, lane = tid & 63;
    int sub = lane >> 4;   // edge subset 0..3
    int fl = lane & 15;    // 16B feature chunk
    for (int nl = wave; nl < BNODES; nl += 4) {
        int node = bk * BNODES + nl;
        int c = hist[nl];
        if (c > PAD) c = PAD;
        int nb = nl * PAD;
        float s[8];
#pragma unroll
        for (int i = 0; i < 8; ++i) s[i] = 0.f;

        for (int e = 0; e < c; e += 16) {
            int cm1 = c - 1;
            int e0 = e + sub, e1 = e + 4 + sub, e2 = e + 8 + sub, e3 = e + 12 + sub;
            int a0 = img[nb + imin(e0, cm1)];
            int a1 = img[nb + imin(e1, cm1)];
            int a2 = img[nb + imin(e2, cm1)];
            int a3 = img[nb + imin(e3, cm1)];
            uint4 u0 = P4[(size_t)a0 * 16 + fl];
            uint4 u1 = P4[(size_t)a1 * 16 + fl];
            uint4 u2 = P4[(size_t)a2 * 16 + fl];
            uint4 u3 = P4[(size_t)a3 * 16 + fl];
            if (e0 < c) acc8(s, u0);
            if (e1 < c) acc8(s, u1);
            if (e2 < c) acc8(s, u2);
            if (e3 < c) acc8(s, u3);
        }
        // reduce across the 4 edge-subsets (lanes differing in bits 4,5)
#pragma unroll
        for (int i = 0; i < 8; ++i) s[i] += __shfl_xor(s[i], 16);
#pragma unroll
        for (int i = 0; i < 8; ++i) s[i] += __shfl_xor(s[i], 32);

        if (sub == 0) {
            float ic = 1.0f / (float)(c > 0 ? c : 1);
            uint4 su = S4[(size_t)node * 16 + fl];
            float4 bA = *(const float4*)&b1[fl * 8];
            float4 bB = *(const float4*)&b1[fl * 8 + 4];
            float sv[8];
            sv[0] = bf_lo(su.x); sv[1] = bf_hi(su.x);
            sv[2] = bf_lo(su.y); sv[3] = bf_hi(su.y);
            sv[4] = bf_lo(su.z); sv[5] = bf_hi(su.z);
            sv[6] = bf_lo(su.w); sv[7] = bf_hi(su.w);
            float bb[8] = {bA.x, bA.y, bA.z, bA.w, bB.x, bB.y, bB.z, bB.w};
            float v[8];
#pragma unroll
            for (int i = 0; i < 8; ++i) v[i] = fmaxf(fmaf(s[i], ic, bb[i] + sv[i]), 0.f);
            uint4 o;
            o.x = (uint32)f2bf(v[0]) | ((uint32)f2bf(v[1]) << 16);
            o.y = (uint32)f2bf(v[2]) | ((uint32)f2bf(v[3]) << 16);
            o.z = (uint32)f2bf(v[4]) | ((uint32)f2bf(v[5]) << 16);
            o.w = (uint32)f2bf(v[6]) | ((uint32)f2bf(v[7]) << 16);
            hbf4[(size_t)node * 16 + fl] = o;
        }
    }
}

// ---------------- layer-2 aggregation: bucket-WG, LDS CSR regroup + 4-deep gathers ----
// P4: T2l [N][8] uint4 (64 bf16). selfR2: fp32 [N][64]. out: fp32 [N][64].
__global__ __launch_bounds__(256) void agg2_kernel(const uint4* __restrict__ P4,
                                                   const float* __restrict__ selfR2,
                                                   const int* __restrict__ bstream,
                                                   const int* __restrict__ gcur,
                                                   const float* __restrict__ b2,
                                                   float* __restrict__ out) {
    __shared__ int img[BNODES * PAD];  // 12.8 KB
    __shared__ int hist[BNODES];
    int tid = threadIdx.x, bk = blockIdx.x;
    for (int i = tid; i < BNODES; i += 256) hist[i] = 0;
    __syncthreads();
    int n = gcur[bk * GSTR];
    if (n > BCAP) n = BCAP;
    for (int i = tid; i < n; i += 256) {
        int u = bstream[bk * BCAP + i];
        int dl = u & 255;
        int r = atomicAdd(&hist[dl], 1);
        if (r < PAD) img[dl * PAD + r] = u >> 8;
    }
    __syncthreads();

    int wave = tid >> 6, lane = tid & 63;
    int sub = lane >> 3;  // edge subset 0..7
    int fl = lane & 7;    // 16B feature chunk
    for (int nl = wave; nl < BNODES; nl += 4) {
        int node = bk * BNODES + nl;
        int c = hist[nl];
        if (c > PAD) c = PAD;
        int nb = nl * PAD;
        float s[8];
#pragma unroll
        for (int i = 0; i < 8; ++i) s[i] = 0.f;

        for (int e = 0; e < c; e += 32) {
            int cm1 = c - 1;
            int e0 = e + sub, e1 = e + 8 + sub, e2 = e + 16 + sub, e3 = e + 24 + sub;
            int a0 = img[nb + imin(e0, cm1)];
            int a1 = img[nb + imin(e1, cm1)];
            int a2 = img[nb + imin(e2, cm1)];
            int a3 = img[nb + imin(e3, cm1)];
            uint4 u0 = P4[(size_t)a0 * 8 + fl];
            uint4 u1 = P4[(size_t)a1 * 8 + fl];
            uint4 u2 = P4[(size_t)a2 * 8 + fl];
            uint4 u3 = P4[(size_t)a3 * 8 + fl];
            if (e0 < c) acc8(s, u0);
            if (e1 < c) acc8(s, u1);
            if (e2 < c) acc8(s, u2);
            if (e3 < c) acc8(s, u3);
        }
#pragma unroll
        for (int i = 0; i < 8; ++i) s[i] += __shfl_xor(s[i], 8);
#pragma unroll
        for (int i = 0; i < 8; ++i) s[i] += __shfl_xor(s[i], 16);
#pragma unroll
        for (int i = 0; i < 8; ++i) s[i] += __shfl_xor(s[i], 32);

        if (sub == 0) {
            float ic = 1.0f / (float)(c > 0 ? c : 1);
            float4 sA = *(const float4*)&selfR2[(size_t)node * 64 + fl * 8];
            float4 sB = *(const float4*)&selfR2[(size_t)node * 64 + fl * 8 + 4];
            float4 bA = *(const float4*)&b2[fl * 8];
            float4 bB = *(const float4*)&b2[fl * 8 + 4];
            float sv[8] = {sA.x, sA.y, sA.z, sA.w, sB.x, sB.y, sB.z, sB.w};
            float bb[8] = {bA.x, bA.y, bA.z, bA.w, bB.x, bB.y, bB.z, bB.w};
            float v[8];
#pragma unroll
            for (int i = 0; i < 8; ++i) v[i] = fmaf(s[i], ic, bb[i] + sv[i]);
            float4 o0 = make_float4(v[0], v[1], v[2], v[3]);
            float4 o1 = make_float4(v[4], v[5], v[6], v[7]);
            *(float4*)&out[(size_t)node * 64 + fl * 8] = o0;
            *(float4*)&out[(size_t)node * 64 + fl * 8 + 4] = o1;
        }
    }
}

extern "C" void kernel_launch(void* const* d_in, const int* in_sizes, int n_in,
                              void* d_out, int out_size, void* d_ws, size_t ws_size,
                              hipStream_t stream) {
    const float* x   = (const float*)d_in[0];
    const void*  ei  = d_in[1];
    const float* W1l = (const float*)d_in[2];
    const float* b1  = (const float*)d_in[3];
    const float* W1r = (const float*)d_in[4];
    const float* W2l = (const float*)d_in[5];
    const float* b2  = (const float*)d_in[6];
    const float* W2r = (const float*)d_in[7];
    float* out = (float*)d_out;

    char* p = (char*)d_ws;
    auto alloc = [&](size_t bytes) {
        char* r = p;
        p += (bytes + 255) & ~(size_t)255;
        return r;
    };
    int*      flag      = (int*)alloc(4);
    int*      gcur      = (int*)alloc((size_t)NBK * GSTR * 4);        // 51.2 KB (line-padded)
    int*      bstream   = (int*)alloc((size_t)NBK * BCAP * 4);        // 4.10 MB
    ushort16* Wfrag1    = (ushort16*)alloc(32768 * 2);
    ushort16* Wfrag2    = (ushort16*)alloc(16384 * 2);
    uint32*   xbf       = (uint32*)alloc((size_t)NNODES * 64 * 4);    // x bf16
    ushort16* T1l       = (ushort16*)alloc((size_t)NNODES * 128 * 2); // bf16 payload
    ushort16* T1r       = (ushort16*)alloc((size_t)NNODES * 128 * 2); // bf16 self
    uint32*   hbf       = (uint32*)alloc((size_t)NNODES * 64 * 4);    // h bf16
    ushort16* T2l       = (ushort16*)alloc((size_t)NNODES * 64 * 2);
    float*    T2r       = (float*)alloc((size_t)NNODES * 64 * 4);

    // fused conv+pack+flag+gcur-zero
    prep_kernel<<<5192, 256, 0, stream>>>(x, xbf, gcur, W1l, W1r, W2l, W2r, Wfrag1, Wfrag2,
                                          (const int*)ei, flag);
    // radix partition into 800 bucket streams
    buildA_kernel<<<AWGS, 256, 0, stream>>>(ei, flag, gcur, bstream);

    // layer 1: T1 = xbf @ [W1l | W1r]; left 128 -> bf16 payload, right 128 -> bf16 self
    gemm_mfma_kernel<<<dim3(NNODES / 64, 2), 256, 0, stream>>>(
        (const ushort16*)xbf, (const uint4*)Wfrag1, 128, 128, T1l, T1r, (float*)nullptr);
    agg1_kernel<<<NBK, 256, 0, stream>>>((const uint4*)T1l, (const uint4*)T1r, bstream, gcur,
                                         b1, (uint4*)hbf);

    // layer 2: T2 = hbf @ [W2l | W2r]; left 64 -> bf16 payload, right 64 -> fp32 self
    gemm_mfma_kernel<<<dim3(NNODES / 64, 1), 256, 0, stream>>>(
        (const ushort16*)hbf, (const uint4*)Wfrag2, 64, 64, T2l, (ushort16*)nullptr, T2r);
    agg2_kernel<<<NBK, 256, 0, stream>>>((const uint4*)T2l, T2r, bstream, gcur, b2, out);
}

// Round 6
// 172.995 us; speedup vs baseline: 1.0739x; 1.0739x over previous
//
#include <hip/hip_runtime.h>

#define NNODES 40000
#define NEDGES 640000
#define PAD 64
#define NBK 160           // dst-range buckets
#define BNODES 250        // nodes per bucket (160*250 = 40000)
#define BCAP 8192         // bucket stream capacity (mean 4000, Poisson)
#define ACHUNK 4000       // edges per buildA WG (160*4000 = 640000)
// IN_F = 128, HID = 128, OUT_F = 64

typedef unsigned int uint32;
typedef unsigned short ushort16;
typedef short bf16x8 __attribute__((ext_vector_type(8)));
typedef float f32x4 __attribute__((ext_vector_type(4)));

// ---------------- bf16 helpers ----------------
static __device__ __forceinline__ ushort16 f2bf(float f) {
    uint32 u = __builtin_bit_cast(uint32, f);
    uint32 r = u + 0x7fffu + ((u >> 16) & 1u);  // RNE
    return (ushort16)(r >> 16);
}
static __device__ __forceinline__ float bf_lo(uint32 u) {
    uint32 t = u << 16;
    return __builtin_bit_cast(float, t);
}
static __device__ __forceinline__ float bf_hi(uint32 u) {
    uint32 t = u & 0xffff0000u;
    return __builtin_bit_cast(float, t);
}

static __device__ __forceinline__ void acc8(float* s, uint4 u) {
    s[0] += bf_lo(u.x); s[1] += bf_hi(u.x);
    s[2] += bf_lo(u.y); s[3] += bf_hi(u.y);
    s[4] += bf_lo(u.z); s[5] += bf_hi(u.z);
    s[6] += bf_lo(u.w); s[7] += bf_hi(u.w);
}

static __device__ __forceinline__ int edge_val(const void* ep, long long idx, int is64) {
    if (is64) return (int)((const long long*)ep)[idx];
    return ((const int*)ep)[idx];
}

static __device__ __forceinline__ int imin(int a, int b) { return a < b ? a : b; }

// ---------------- fused prep: x -> bf16 AND weight packing + dtype flag + gcur zero ----
// blocks [0, 5000): conv part (n4 = 1,280,000 float4 = exactly 5000*256)
// blocks [5000, 5192): pack part (49152 threads)
__global__ void prep_kernel(const float* __restrict__ x, uint32* __restrict__ xbf2,
                            int* __restrict__ gcur,
                            const float* __restrict__ W1l, const float* __restrict__ W1r,
                            const float* __restrict__ W2l, const float* __restrict__ W2r,
                            ushort16* __restrict__ Wfrag1, ushort16* __restrict__ Wfrag2,
                            const int* __restrict__ e32, int* __restrict__ flag) {
    int b = blockIdx.x;
    if (b < 5000) {
        int i = b * 256 + threadIdx.x;
        float4 v = ((const float4*)x)[i];
        uint2 o;
        o.x = (uint32)f2bf(v.x) | ((uint32)f2bf(v.y) << 16);
        o.y = (uint32)f2bf(v.z) | ((uint32)f2bf(v.w) << 16);
        ((uint2*)xbf2)[i] = o;
        return;
    }
    int i = (b - 5000) * 256 + threadIdx.x;  // 49152 total
    if (i < NBK) gcur[i] = 0;
    if (i == 0) {
        int any = 0;
        for (int t = 0; t < 64; ++t) any |= e32[2 * t + 1];
        *flag = (any == 0) ? 1 : 0;
    }
    if (i < 32768) {
        int j = i & 7, lane = (i >> 3) & 63, nt = (i >> 9) & 7, s = (i >> 12) & 3, by = i >> 14;
        int k = s * 32 + (lane >> 4) * 8 + j;
        int col = nt * 16 + (lane & 15);
        float v = (by == 0) ? W1l[k * 128 + col] : W1r[k * 128 + col];
        Wfrag1[i] = f2bf(v);
    } else {
        int q = i - 32768;  // 16384
        int j = q & 7, lane = (q >> 3) & 63, nt = (q >> 9) & 7, s = (q >> 12) & 3;
        int k = s * 32 + (lane >> 4) * 8 + j;
        int col = nt * 16 + (lane & 15);
        float v = (col < 64) ? W2l[k * 64 + col] : W2r[k * 64 + (col - 64)];
        Wfrag2[q] = f2bf(v);
    }
}

// ---------------- buildA: radix partition edges into 160 dst-range bucket streams ----
// Temporal write locality inside one WG (no XCD-mapping assumption): each WG
// reserves a private contiguous range per bucket and appends ~25-entry runs.
// Entry packs (src<<8)|dloc, dloc = d - bucket*250 < 250.
__global__ __launch_bounds__(256) void buildA_kernel(const void* __restrict__ edges,
                                                     const int* __restrict__ flag,
                                                     int* __restrict__ gcur,
                                                     int* __restrict__ bstream) {
    __shared__ int hist[NBK];
    __shared__ int cur[NBK];
    int tid = threadIdx.x;
    int base = blockIdx.x * ACHUNK;
    for (int i = tid; i < NBK; i += 256) hist[i] = 0;
    __syncthreads();
    int is64 = *flag;
    // pass 1: count buckets in this chunk
#pragma unroll
    for (int k = 0; k < (ACHUNK + 255) / 256; ++k) {
        int off = k * 256 + tid;
        if (off < ACHUNK) {
            int d = edge_val(edges, (long long)NEDGES + base + off, is64);
            atomicAdd(&hist[d / BNODES], 1);
        }
    }
    __syncthreads();
    if (tid < NBK) cur[tid] = atomicAdd(&gcur[tid], hist[tid]);
    __syncthreads();
    // pass 2: re-read (L2-hot) and append
#pragma unroll
    for (int k = 0; k < (ACHUNK + 255) / 256; ++k) {
        int off = k * 256 + tid;
        if (off < ACHUNK) {
            int e = base + off;
            int d = edge_val(edges, (long long)NEDGES + e, is64);
            int s = edge_val(edges, e, is64);
            int bk = d / BNODES;
            int dloc = d - bk * BNODES;
            int r = atomicAdd(&cur[bk], 1);
            if (r < BCAP) bstream[bk * BCAP + r] = (s << 8) | dloc;
        }
    }
}

// ---------------- buildB: per-bucket LDS regroup -> dense padded-CSR writeback ----
// One WG per bucket: scatter entries into a 64 KB LDS image (250 nodes x 64
// slots) with LDS atomics, then write the image densely (int4). Unused slots
// are garbage but never read (agg clamps to cnt). All random scatter is in LDS.
__global__ __launch_bounds__(256) void buildB_kernel(const int* __restrict__ bstream,
                                                     const int* __restrict__ gcur,
                                                     int* __restrict__ cnt,
                                                     int* __restrict__ csr_src) {
    __shared__ int4 img4[BNODES * 16];  // 64000 B
    __shared__ int hist[BNODES];        // 1000 B
    int* img = (int*)img4;
    int tid = threadIdx.x;
    int bk = blockIdx.x;
    for (int i = tid; i < BNODES; i += 256) hist[i] = 0;
    __syncthreads();
    int n = gcur[bk];
    if (n > BCAP) n = BCAP;
    for (int i = tid; i < n; i += 256) {
        int u = bstream[bk * BCAP + i];
        int dloc = u & 255;
        int s = u >> 8;
        int r = atomicAdd(&hist[dloc], 1);
        if (r < PAD) img[dloc * PAD + r] = s;
    }
    __syncthreads();
    int4* csr4 = (int4*)csr_src;
#pragma unroll
    for (int i = tid; i < BNODES * 16; i += 256) csr4[(size_t)bk * BNODES * 16 + i] = img4[i];
    for (int i = tid; i < BNODES; i += 256) cnt[bk * BNODES + i] = hist[i];
}

// ---------------- MFMA GEMM: C[40000][CO] = Abf[40000][128] @ W ----------------
// block = 256 threads = 4 waves; tile = 64 rows x 128 cols.
// Left cols (< Lw) -> bf16 bfL; right cols -> bf16 bfR (if non-null) else fp32 fR.
__global__ __launch_bounds__(256) void gemm_mfma_kernel(const ushort16* __restrict__ Abf,
                                                        const uint4* __restrict__ WfragG,
                                                        int Lw, int Rw,
                                                        ushort16* __restrict__ bfL,
                                                        ushort16* __restrict__ bfR,
                                                        float* __restrict__ fR) {
    __shared__ uint4 Bs[2048];  // 32 KB
    int tid = threadIdx.x;
#pragma unroll
    for (int it = 0; it < 8; ++it) {
        int idx = tid + it * 256;
        Bs[idx] = WfragG[(size_t)blockIdx.y * 2048 + idx];
    }

    int wv = tid >> 6, lane = tid & 63;
    int quad = lane >> 4, c = lane & 15;
    int row0 = blockIdx.x * 64 + wv * 16;

    const uint4* arow = (const uint4*)(Abf + (size_t)(row0 + c) * 128);
    bf16x8 af[4];
#pragma unroll
    for (int s = 0; s < 4; ++s) af[s] = __builtin_bit_cast(bf16x8, arow[s * 4 + quad]);

    __syncthreads();

    f32x4 acc[8];
#pragma unroll
    for (int nt = 0; nt < 8; ++nt) acc[nt] = (f32x4){0.f, 0.f, 0.f, 0.f};

#pragma unroll
    for (int s = 0; s < 4; ++s) {
#pragma unroll
        for (int nt = 0; nt < 8; ++nt) {
            bf16x8 bf = __builtin_bit_cast(bf16x8, Bs[(s * 8 + nt) * 64 + lane]);
            acc[nt] = __builtin_amdgcn_mfma_f32_16x16x32_bf16(af[s], bf, acc[nt], 0, 0, 0);
        }
    }

    int colbase = blockIdx.y * 128;
#pragma unroll
    for (int nt = 0; nt < 8; ++nt) {
        int gcol = colbase + nt * 16 + c;
#pragma unroll
        for (int r = 0; r < 4; ++r) {
            int row = row0 + quad * 4 + r;
            if (gcol < Lw) {
                bfL[(size_t)row * Lw + gcol] = f2bf(acc[nt][r]);
            } else if (bfR) {
                bfR[(size_t)row * Rw + (gcol - Lw)] = f2bf(acc[nt][r]);
            } else {
                fR[(size_t)row * Rw + (gcol - Lw)] = acc[nt][r];
            }
        }
    }
}

// ---------------- layer-1 aggregation: one wave per node, 4-deep uint4 gathers --------
// P4: T1l [N][16] uint4 (128 bf16). S4: T1r bf16 [N][16] uint4. Out hbf4: [N][16] uint4.
// 16-edge groups, 4 gathers in flight; out-of-range slots clamp their shuffle
// index to c-1 (duplicate address -> L1/L2 hit, not HBM bytes) and are
// predicated out of the accumulate.
__global__ __launch_bounds__(256) void agg1_kernel(const uint4* __restrict__ P4,
                                                   const uint4* __restrict__ S4,
                                                   const int* __restrict__ cnt,
                                                   const int* __restrict__ csr_src,
                                                   const float* __restrict__ b1,
                                                   uint4* __restrict__ hbf4) {
    int wave = threadIdx.x >> 6, lane = threadIdx.x & 63;
    int node = blockIdx.x * 4 + wave;
    if (node >= NNODES) return;
    int c = cnt[node];
    if (c > PAD) c = PAD;
    int beg = node * PAD;
    int sub = lane >> 4;   // edge subset 0..3
    int fl = lane & 15;    // 16B feature chunk
    float s[8];
#pragma unroll
    for (int i = 0; i < 8; ++i) s[i] = 0.f;

    int idx = csr_src[beg + lane];  // padded bucket: always in-bounds
    int cm1 = c - 1;
    for (int e = 0; e < c; e += 16) {
        int e0 = e + sub, e1 = e + 4 + sub, e2 = e + 8 + sub, e3 = e + 12 + sub;
        int a0 = __shfl(idx, imin(e0, cm1));
        int a1 = __shfl(idx, imin(e1, cm1));
        int a2 = __shfl(idx, imin(e2, cm1));
        int a3 = __shfl(idx, imin(e3, cm1));
        uint4 u0 = P4[(size_t)a0 * 16 + fl];
        uint4 u1 = P4[(size_t)a1 * 16 + fl];
        uint4 u2 = P4[(size_t)a2 * 16 + fl];
        uint4 u3 = P4[(size_t)a3 * 16 + fl];
        if (e0 < c) acc8(s, u0);
        if (e1 < c) acc8(s, u1);
        if (e2 < c) acc8(s, u2);
        if (e3 < c) acc8(s, u3);
    }
    // reduce across the 4 edge-subsets (lanes differing in bits 4,5)
#pragma unroll
    for (int i = 0; i < 8; ++i) s[i] += __shfl_xor(s[i], 16);
#pragma unroll
    for (int i = 0; i < 8; ++i) s[i] += __shfl_xor(s[i], 32);

    if (sub == 0) {
        float ic = 1.0f / (float)(c > 0 ? c : 1);
        uint4 su = S4[(size_t)node * 16 + fl];
        float4 bA = *(const float4*)&b1[fl * 8];
        float4 bB = *(const float4*)&b1[fl * 8 + 4];
        float sv[8];
        sv[0] = bf_lo(su.x); sv[1] = bf_hi(su.x);
        sv[2] = bf_lo(su.y); sv[3] = bf_hi(su.y);
        sv[4] = bf_lo(su.z); sv[5] = bf_hi(su.z);
        sv[6] = bf_lo(su.w); sv[7] = bf_hi(su.w);
        float bb[8] = {bA.x, bA.y, bA.z, bA.w, bB.x, bB.y, bB.z, bB.w};
        float v[8];
#pragma unroll
        for (int i = 0; i < 8; ++i) v[i] = fmaxf(fmaf(s[i], ic, bb[i] + sv[i]), 0.f);
        uint4 o;
        o.x = (uint32)f2bf(v[0]) | ((uint32)f2bf(v[1]) << 16);
        o.y = (uint32)f2bf(v[2]) | ((uint32)f2bf(v[3]) << 16);
        o.z = (uint32)f2bf(v[4]) | ((uint32)f2bf(v[5]) << 16);
        o.w = (uint32)f2bf(v[6]) | ((uint32)f2bf(v[7]) << 16);
        hbf4[(size_t)node * 16 + fl] = o;
    }
}

// ---------------- layer-2 aggregation: one wave per node, 4-deep uint4 gathers --------
// P4: T2l [N][8] uint4 (64 bf16). selfR2: fp32 [N][64]. out: fp32 [N][64].
__global__ __launch_bounds__(256) void agg2_kernel(const uint4* __restrict__ P4,
                                                   const float* __restrict__ selfR2,
                                                   const int* __restrict__ cnt,
                                                   const int* __restrict__ csr_src,
                                                   const float* __restrict__ b2,
                                                   float* __restrict__ out) {
    int wave = threadIdx.x >> 6, lane = threadIdx.x & 63;
    int node = blockIdx.x * 4 + wave;
    if (node >= NNODES) return;
    int c = cnt[node];
    if (c > PAD) c = PAD;
    int beg = node * PAD;
    int sub = lane >> 3;  // edge subset 0..7
    int fl = lane & 7;    // 16B feature chunk
    float s[8];
#pragma unroll
    for (int i = 0; i < 8; ++i) s[i] = 0.f;

    int idx = csr_src[beg + lane];  // padded bucket: always in-bounds
    int cm1 = c - 1;
    for (int e = 0; e < c; e += 32) {
        int e0 = e + sub, e1 = e + 8 + sub, e2 = e + 16 + sub, e3 = e + 24 + sub;
        int a0 = __shfl(idx, imin(e0, cm1));
        int a1 = __shfl(idx, imin(e1, cm1));
        int a2 = __shfl(idx, imin(e2, cm1));
        int a3 = __shfl(idx, imin(e3, cm1));
        uint4 u0 = P4[(size_t)a0 * 8 + fl];
        uint4 u1 = P4[(size_t)a1 * 8 + fl];
        uint4 u2 = P4[(size_t)a2 * 8 + fl];
        uint4 u3 = P4[(size_t)a3 * 8 + fl];
        if (e0 < c) acc8(s, u0);
        if (e1 < c) acc8(s, u1);
        if (e2 < c) acc8(s, u2);
        if (e3 < c) acc8(s, u3);
    }
#pragma unroll
    for (int i = 0; i < 8; ++i) s[i] += __shfl_xor(s[i], 8);
#pragma unroll
    for (int i = 0; i < 8; ++i) s[i] += __shfl_xor(s[i], 16);
#pragma unroll
    for (int i = 0; i < 8; ++i) s[i] += __shfl_xor(s[i], 32);

    if (sub == 0) {
        float ic = 1.0f / (float)(c > 0 ? c : 1);
        float4 sA = *(const float4*)&selfR2[(size_t)node * 64 + fl * 8];
        float4 sB = *(const float4*)&selfR2[(size_t)node * 64 + fl * 8 + 4];
        float4 bA = *(const float4*)&b2[fl * 8];
        float4 bB = *(const float4*)&b2[fl * 8 + 4];
        float sv[8] = {sA.x, sA.y, sA.z, sA.w, sB.x, sB.y, sB.z, sB.w};
        float bb[8] = {bA.x, bA.y, bA.z, bA.w, bB.x, bB.y, bB.z, bB.w};
        float v[8];
#pragma unroll
        for (int i = 0; i < 8; ++i) v[i] = fmaf(s[i], ic, bb[i] + sv[i]);
        float4 o0 = make_float4(v[0], v[1], v[2], v[3]);
        float4 o1 = make_float4(v[4], v[5], v[6], v[7]);
        *(float4*)&out[(size_t)node * 64 + fl * 8] = o0;
        *(float4*)&out[(size_t)node * 64 + fl * 8 + 4] = o1;
    }
}

extern "C" void kernel_launch(void* const* d_in, const int* in_sizes, int n_in,
                              void* d_out, int out_size, void* d_ws, size_t ws_size,
                              hipStream_t stream) {
    const float* x   = (const float*)d_in[0];
    const void*  ei  = d_in[1];
    const float* W1l = (const float*)d_in[2];
    const float* b1  = (const float*)d_in[3];
    const float* W1r = (const float*)d_in[4];
    const float* W2l = (const float*)d_in[5];
    const float* b2  = (const float*)d_in[6];
    const float* W2r = (const float*)d_in[7];
    float* out = (float*)d_out;

    char* p = (char*)d_ws;
    auto alloc = [&](size_t bytes) {
        char* r = p;
        p += (bytes + 255) & ~(size_t)255;
        return r;
    };
    int*      flag      = (int*)alloc(4);
    int*      cnt       = (int*)alloc(NNODES * 4);
    int*      gcur      = (int*)alloc(NBK * 4);
    int*      bstream   = (int*)alloc((size_t)NBK * BCAP * 4);        // 5.24 MB
    int*      csr_src   = (int*)alloc((size_t)NNODES * PAD * 4);      // padded CSR, 10.24 MB
    ushort16* Wfrag1    = (ushort16*)alloc(32768 * 2);
    ushort16* Wfrag2    = (ushort16*)alloc(16384 * 2);
    uint32*   xbf       = (uint32*)alloc((size_t)NNODES * 64 * 4);    // x bf16
    ushort16* T1l       = (ushort16*)alloc((size_t)NNODES * 128 * 2); // bf16 payload
    ushort16* T1r       = (ushort16*)alloc((size_t)NNODES * 128 * 2); // bf16 self
    uint32*   hbf       = (uint32*)alloc((size_t)NNODES * 64 * 4);    // h bf16
    ushort16* T2l       = (ushort16*)alloc((size_t)NNODES * 64 * 2);
    float*    T2r       = (float*)alloc((size_t)NNODES * 64 * 4);

    // fused conv+pack+flag+gcur-zero
    prep_kernel<<<5192, 256, 0, stream>>>(x, xbf, gcur, W1l, W1r, W2l, W2r, Wfrag1, Wfrag2,
                                          (const int*)ei, flag);
    // radix CSR build: partition into bucket streams, then LDS regroup + dense writeback
    buildA_kernel<<<NBK, 256, 0, stream>>>(ei, flag, gcur, bstream);
    buildB_kernel<<<NBK, 256, 0, stream>>>(bstream, gcur, cnt, csr_src);

    // layer 1: T1 = xbf @ [W1l | W1r]; left 128 -> bf16 payload, right 128 -> bf16 self
    gemm_mfma_kernel<<<dim3(NNODES / 64, 2), 256, 0, stream>>>(
        (const ushort16*)xbf, (const uint4*)Wfrag1, 128, 128, T1l, T1r, (float*)nullptr);
    agg1_kernel<<<(NNODES + 3) / 4, 256, 0, stream>>>((const uint4*)T1l, (const uint4*)T1r,
                                                      cnt, csr_src, b1, (uint4*)hbf);

    // layer 2: T2 = hbf @ [W2l | W2r]; left 64 -> bf16 payload, right 64 -> fp32 self
    gemm_mfma_kernel<<<dim3(NNODES / 64, 1), 256, 0, stream>>>(
        (const ushort16*)hbf, (const uint4*)Wfrag2, 64, 64, T2l, (ushort16*)nullptr, T2r);
    agg2_kernel<<<(NNODES + 3) / 4, 256, 0, stream>>>((const uint4*)T2l, T2r, cnt, csr_src, b2,
                                                      out);
}